// Round 18
// baseline (64.830 us; speedup 1.0000x reference)
//
#include <hip/hip_runtime.h>

#define LC 2048
#define DD 128
#define LQ 64
#define NPART 16
#define PAD 136

typedef unsigned short u16;
typedef unsigned int u32;
typedef __attribute__((ext_vector_type(8))) short bf16x8;
typedef __attribute__((ext_vector_type(4))) float f32x4;
typedef __attribute__((ext_vector_type(4))) _Float16 f16x4;

__device__ inline float b2f(u16 u) { return __uint_as_float(((u32)u) << 16); }
// pack2(a,b): a -> low 16, b -> high 16, RNE. Single HW instr on gfx950.
__device__ inline u32 pack2(float a, float b) {
  u32 r;
  asm("v_cvt_pk_bf16_f32 %0, %1, %2" : "=v"(r) : "v"(a), "v"(b));
  return r;
}

// K13: 128-i chunk, 8 waves, 52KB LDS, forced 6 waves/EU (3 blocks/CU)
__global__ __launch_bounds__(512, 6) void k13(const float* __restrict__ C,
                                              const float* __restrict__ Q,
                                              const float* __restrict__ w,
                                              const float* __restrict__ qmask,
                                              u16* __restrict__ S1g,
                                              _Float16* __restrict__ Tu_part,
                                              float* __restrict__ Z_part, int B) {
  __shared__ u16 ldsA[128 * PAD];  // phase1: C^T[i][d], pads: sc partials
  __shared__ u16 ldsB[64 * PAD];   // phase1: Qw^T[j][d], pads: sq partials -> inv[i]
  __shared__ float scL[128];
  __shared__ float sqs[64];
  __shared__ float mkS[64];
  int b = blockIdx.y, bx = blockIdx.x;
  int i0 = bx * 128, t = threadIdx.x;
  const float* Cb = C + (size_t)b * DD * LC;
  const float* Qb = Q + (size_t)b * DD * LQ;
  if (t < 64) mkS[t] = qmask[b * LQ + t];
  // --- phase 1 staging: C^T (bf16, transposed) + sc partials in ldsA pads ---
  {
    int i_st = t & 127, dh = t >> 7;  // dh in [0,4): 32 d each
    const float* Cp = Cb + (size_t)dh * 32 * LC + i0 + i_st;
    float scp = 0.f;
#pragma unroll
    for (int dp = 0; dp < 16; ++dp) {
      int d = dh * 32 + 2 * dp;
      float c0 = Cp[(size_t)(2 * dp) * LC];
      float c1 = Cp[(size_t)(2 * dp + 1) * LC];
      scp = fmaf(c0, w[d], fmaf(c1, w[d + 1], scp));
      *(u32*)&ldsA[i_st * PAD + d] = pack2(c0, c1);
    }
    *(float*)&ldsA[i_st * PAD + 128 + dh * 2] = scp;
  }
  // Qw^T staging on waves 0-3 + sq partials in ldsB pads
  if (t < 256) {
    int j = t & 63, dg = t >> 6;  // dg in [0,4): 32 d each
    const float* Qp = Qb + j;
    float sqp = 0.f;
#pragma unroll
    for (int dp = 0; dp < 16; ++dp) {
      int d = dg * 32 + 2 * dp;
      float q0 = Qp[(size_t)d * LQ];
      float q1 = Qp[(size_t)(d + 1) * LQ];
      sqp = fmaf(q0, w[DD + d], fmaf(q1, w[DD + d + 1], sqp));
      *(u32*)&ldsB[j * PAD + d] = pack2(q0 * w[2 * DD + d], q1 * w[2 * DD + d + 1]);
    }
    *(float*)&ldsB[j * PAD + 128 + dg * 2] = sqp;
  }
  __syncthreads();
  if (t < 128) {
    float4 p = *(const float4*)&ldsA[t * PAD + 128];
    scL[t] = (p.x + p.y) + (p.z + p.w);
  } else if (t < 192) {
    int j = t - 128;
    float4 p = *(const float4*)&ldsB[j * PAD + 128];
    sqs[j] = (p.x + p.y) + (p.z + p.w);
  }
  // --- phase 2: S-GEMM; wave wv owns m-tile wv (16 i rows) ---
  int lane = t & 63, wv = t >> 6;
  int lr = lane & 15, kg = lane >> 4;
  f32x4 acc[4];
#pragma unroll
  for (int nt = 0; nt < 4; ++nt) acc[nt] = (f32x4){0.f, 0.f, 0.f, 0.f};
#pragma unroll
  for (int ks = 0; ks < 4; ++ks) {
    bf16x8 af = *(bf16x8*)&ldsA[(wv * 16 + lr) * PAD + ks * 32 + kg * 8];
    bf16x8 bf[4];
#pragma unroll
    for (int nt = 0; nt < 4; ++nt)
      bf[nt] = *(bf16x8*)&ldsB[(nt * 16 + lr) * PAD + ks * 32 + kg * 8];
#pragma unroll
    for (int nt = 0; nt < 4; ++nt)
      acc[nt] = __builtin_amdgcn_mfma_f32_16x16x32_bf16(af, bf[nt], acc[nt], 0, 0, 0);
  }
  __syncthreads();  // all MFMA reads done; scL/sqs final
  // --- epilogue: E=exp(S+sc+sq); rowsum(mask*E) -> inv; E^T -> ldsB ---
  {
    int ib = wv * 16 + kg * 4;
    float ev[4][4];
    float ps[4] = {0.f, 0.f, 0.f, 0.f};
#pragma unroll
    for (int nt = 0; nt < 4; ++nt) {
      int j = nt * 16 + lr;
      float sqv = sqs[j];
      float mkv = mkS[j];
#pragma unroll
      for (int r = 0; r < 4; ++r) {
        float e = __expf(acc[nt][r] + scL[ib + r] + sqv);
        ev[nt][r] = e;
        ps[r] = fmaf(mkv, e, ps[r]);
      }
    }
#pragma unroll
    for (int r = 0; r < 4; ++r) {
      ps[r] += __shfl_xor(ps[r], 1, 64);
      ps[r] += __shfl_xor(ps[r], 2, 64);
      ps[r] += __shfl_xor(ps[r], 4, 64);
      ps[r] += __shfl_xor(ps[r], 8, 64);
    }
#pragma unroll
    for (int nt = 0; nt < 4; ++nt) {
      int j = nt * 16 + lr;
      u32 pk[2] = {pack2(ev[nt][0], ev[nt][1]), pack2(ev[nt][2], ev[nt][3])};
      *(uint2*)&ldsB[j * PAD + ib] = *(uint2*)pk;
    }
    if (lr == 0) {
#pragma unroll
      for (int r = 0; r < 4; ++r) {
        int i = ib + r;
        ((float*)&ldsB[(i & 63) * PAD + 128])[i >> 6] = 1.f / fmaxf(ps[r], 1e-30f);
      }
    }
  }
  // --- Cnat staging: C[d][i] bf16 (overlays ldsA); 32 i per thread ---
  {
    int d = t >> 2, q = t & 3;
    const float* src = Cb + (size_t)d * LC + i0 + q * 32;
    u32 pk[16];
#pragma unroll
    for (int ip = 0; ip < 8; ++ip) {
      float4 v = *(const float4*)&src[ip * 4];
      pk[2 * ip] = pack2(v.x, v.y);
      pk[2 * ip + 1] = pack2(v.z, v.w);
    }
#pragma unroll
    for (int q4 = 0; q4 < 4; ++q4)
      *(uint4*)&ldsA[d * PAD + q * 32 + q4 * 8] = *(uint4*)&pk[q4 * 4];
  }
  __syncthreads();
  // --- phase 3 ---
  // Z[j] over this block's 128 i (b128 LDS reads)
  if (t < 64) {
    const uint4* row = (const uint4*)&ldsB[t * PAD];
    float z = 0.f;
#pragma unroll
    for (int q = 0; q < 16; ++q) {
      uint4 v = row[q];
      z += b2f((u16)v.x) + b2f((u16)(v.x >> 16)) + b2f((u16)v.y) +
           b2f((u16)(v.y >> 16)) + b2f((u16)v.z) + b2f((u16)(v.z >> 16)) +
           b2f((u16)v.w) + b2f((u16)(v.w >> 16));
    }
    Z_part[((size_t)bx * B + b) * LQ + t] = z;
  }
  // S1 dump: S1[i][j] = mask[j]*inv[i]*E[i][j]; 16 j per thread
  {
    int i = t >> 2, q4 = t & 3;
    float inv = ((float*)&ldsB[(i & 63) * PAD + 128])[i >> 6];
    u32 opk[8];
#pragma unroll
    for (int q = 0; q < 8; ++q) {
      int j = q4 * 16 + 2 * q;
      float a0 = b2f(ldsB[j * PAD + i]) * mkS[j] * inv;
      float a1 = b2f(ldsB[(j + 1) * PAD + i]) * mkS[j + 1] * inv;
      opk[q] = pack2(a0, a1);
    }
    u16* dst = S1g + ((size_t)b * LC + i0 + i) * LQ + q4 * 16;
    *(uint4*)&dst[0] = *(uint4*)&opk[0];
    *(uint4*)&dst[8] = *(uint4*)&opk[4];
  }
  // T-GEMM: Tp[j][d] = sum_i E[i][j]*C[d][i]; wave wv owns d m-tile wv
  f32x4 tacc[4];
#pragma unroll
  for (int nt = 0; nt < 4; ++nt) tacc[nt] = (f32x4){0.f, 0.f, 0.f, 0.f};
#pragma unroll
  for (int ks = 0; ks < 4; ++ks) {
    bf16x8 af = *(bf16x8*)&ldsA[(wv * 16 + lr) * PAD + ks * 32 + kg * 8];
    bf16x8 bf[4];
#pragma unroll
    for (int nt = 0; nt < 4; ++nt)
      bf[nt] = *(bf16x8*)&ldsB[(nt * 16 + lr) * PAD + ks * 32 + kg * 8];
#pragma unroll
    for (int nt = 0; nt < 4; ++nt)
      tacc[nt] = __builtin_amdgcn_mfma_f32_16x16x32_bf16(af, bf[nt], tacc[nt], 0, 0, 0);
  }
  _Float16* Tp = Tu_part + ((size_t)bx * B + b) * LQ * DD;
#pragma unroll
  for (int nt = 0; nt < 4; ++nt) {
    int j = nt * 16 + lr;
    int db = wv * 16 + kg * 4;
    f16x4 h;
#pragma unroll
    for (int r = 0; r < 4; ++r) h[r] = (_Float16)tacc[nt][r];
    *(f16x4*)&Tp[(size_t)j * DD + db] = h;
  }
}

// K3b: Tz = (sum_p Tu_part)/Z -> TzT bf16; also Q -> Qbf16[d][j]
__global__ __launch_bounds__(256) void k3b(const _Float16* __restrict__ Tu_part,
                                           const float* __restrict__ Z_part,
                                           const float* __restrict__ Q,
                                           u16* __restrict__ TzT,
                                           u16* __restrict__ Qbf, int B) {
  __shared__ float Tsm[16][68];
  __shared__ float ziL[64];
  int b = blockIdx.y, d0 = blockIdx.x * 16;
  int t = threadIdx.x;
  // Q -> bf16 (independent)
  {
    int dq = d0 + (t >> 4), jq = (t & 15) * 4;
    const float* qp = Q + ((size_t)b * DD + dq) * LQ + jq;
    u32 pk[2] = {pack2(qp[0], qp[1]), pack2(qp[2], qp[3])};
    *(uint2*)&Qbf[((size_t)b * DD + dq) * LQ + jq] = *(uint2*)pk;
  }
  // vectorized partial reduction: thread -> (j, 4 consecutive d)
  {
    int j = t >> 2, dseg = t & 3;
    float acc[4] = {0.f, 0.f, 0.f, 0.f};
#pragma unroll
    for (int p = 0; p < NPART; ++p) {
      f16x4 v = *(const f16x4*)&Tu_part[((size_t)p * B + b) * LQ * DD +
                                        (size_t)j * DD + d0 + dseg * 4];
#pragma unroll
      for (int r = 0; r < 4; ++r) acc[r] += (float)v[r];
    }
#pragma unroll
    for (int r = 0; r < 4; ++r) Tsm[dseg * 4 + r][j] = acc[r];
  }
  if (t < 64) {
    float z = 0.f;
#pragma unroll
    for (int p = 0; p < NPART; ++p) z += Z_part[((size_t)p * B + b) * LQ + t];
    ziL[t] = 1.f / z;
  }
  __syncthreads();
  if (t < 128) {
    int d = t >> 3, seg = t & 7;
    u32 pk[4];
#pragma unroll
    for (int q = 0; q < 4; ++q) {
      int j = seg * 8 + q * 2;
      pk[q] = pack2(Tsm[d][j] * ziL[j], Tsm[d][j + 1] * ziL[j + 1]);
    }
    *(uint4*)&TzT[((size_t)b * DD + d0 + d) * LQ + seg * 8] = *(uint4*)pk;
  }
}

// K4: LDS-free. A-op = S1 rows i, B-op = Q/Tz rows d -> float4 loads/stores.
__global__ __launch_bounds__(256) void k4(const u16* __restrict__ S1g,
                                          const u16* __restrict__ Qbf,
                                          const u16* __restrict__ TzT,
                                          const float* __restrict__ C,
                                          float* __restrict__ out) {
  int b = blockIdx.y, i0 = blockIdx.x * 64, t = threadIdx.x;
  int lane = t & 63, wv = t >> 6;
  int lr = lane & 15, kg = lane >> 4;
  bf16x8 Af[2];
  {
    size_t ri = ((size_t)b * LC + i0 + wv * 16 + lr) * LQ;
    Af[0] = *(const bf16x8*)&S1g[ri + kg * 8];
    Af[1] = *(const bf16x8*)&S1g[ri + 32 + kg * 8];
  }
  const u16* Qb = Qbf + (size_t)b * DD * LQ;
  const u16* Tzb = TzT + (size_t)b * DD * LQ;
  const float* Cb = C + (size_t)b * DD * LC + i0;
  float* outb = out + (size_t)b * 4 * DD * LC + i0;
  int irow = wv * 16 + kg * 4;
#pragma unroll
  for (int nt = 0; nt < 8; ++nt) {
    int d = nt * 16 + lr;
    bf16x8 QB[2], TB[2];
#pragma unroll
    for (int ks = 0; ks < 2; ++ks) {
      QB[ks] = *(const bf16x8*)&Qb[(size_t)d * LQ + ks * 32 + kg * 8];
      TB[ks] = *(const bf16x8*)&Tzb[(size_t)d * LQ + ks * 32 + kg * 8];
    }
    f32x4 accA = {0.f, 0.f, 0.f, 0.f}, accB = {0.f, 0.f, 0.f, 0.f};
    accA = __builtin_amdgcn_mfma_f32_16x16x32_bf16(Af[0], QB[0], accA, 0, 0, 0);
    accA = __builtin_amdgcn_mfma_f32_16x16x32_bf16(Af[1], QB[1], accA, 0, 0, 0);
    accB = __builtin_amdgcn_mfma_f32_16x16x32_bf16(Af[0], TB[0], accB, 0, 0, 0);
    accB = __builtin_amdgcn_mfma_f32_16x16x32_bf16(Af[1], TB[1], accB, 0, 0, 0);
    float4 c4 = *(const float4*)&Cb[(size_t)d * LC + irow];
    float4 oA = make_float4(accA[0], accA[1], accA[2], accA[3]);
    float4 oCA = make_float4(c4.x * accA[0], c4.y * accA[1], c4.z * accA[2],
                             c4.w * accA[3]);
    float4 oCB = make_float4(c4.x * accB[0], c4.y * accB[1], c4.z * accB[2],
                             c4.w * accB[3]);
    *(float4*)&outb[(size_t)d * LC + irow] = c4;
    *(float4*)&outb[(size_t)(DD + d) * LC + irow] = oA;
    *(float4*)&outb[(size_t)(2 * DD + d) * LC + irow] = oCA;
    *(float4*)&outb[(size_t)(3 * DD + d) * LC + irow] = oCB;
  }
}

extern "C" void kernel_launch(void* const* d_in, const int* in_sizes, int n_in,
                              void* d_out, int out_size, void* d_ws, size_t ws_size,
                              hipStream_t stream) {
  const float* C = (const float*)d_in[0];
  const float* Q = (const float*)d_in[1];
  const float* qmask = (const float*)d_in[2];
  const float* w = (const float*)d_in[3];
  float* out = (float*)d_out;
  int B = in_sizes[2] / LQ;

  char* p = (char*)d_ws;
  u16* S1g = (u16*)p;              p += (size_t)B * LC * LQ * 2;
  u16* TzT = (u16*)p;              p += (size_t)B * DD * LQ * 2;
  u16* Qbf = (u16*)p;              p += (size_t)B * DD * LQ * 2;
  _Float16* Tu_part = (_Float16*)p; p += (size_t)NPART * B * LQ * DD * 2;
  float* Z_part = (float*)p;

  k13<<<dim3(LC / 128, B), 512, 0, stream>>>(C, Q, w, qmask, S1g, Tu_part, Z_part, B);
  k3b<<<dim3(DD / 16, B), 256, 0, stream>>>(Tu_part, Z_part, Q, TzT, Qbf, B);
  k4<<<dim3(LC / 64, B), 256, 0, stream>>>(S1g, Qbf, TzT, C, out);
}

// Round 19
// 63.295 us; speedup vs baseline: 1.0242x; 1.0242x over previous
//
#include <hip/hip_runtime.h>

#define LC 2048
#define DD 128
#define LQ 64
#define NPART 16
#define PAD 136

typedef unsigned short u16;
typedef unsigned int u32;
typedef __attribute__((ext_vector_type(8))) short bf16x8;
typedef __attribute__((ext_vector_type(4))) float f32x4;
typedef __attribute__((ext_vector_type(4))) _Float16 f16x4;

__device__ inline float b2f(u16 u) { return __uint_as_float(((u32)u) << 16); }
// pack2(a,b): a -> low 16, b -> high 16, RNE. Single HW instr on gfx950.
__device__ inline u32 pack2(float a, float b) {
  u32 r;
  asm("v_cvt_pk_bf16_f32 %0, %1, %2" : "=v"(r) : "v"(a), "v"(b));
  return r;
}

// K13: 128-i chunk, 8 waves: MFMA S-GEMM + exp + row-softmax -> S1g + Z + T partial
__global__ __launch_bounds__(512) void k13(const float* __restrict__ C,
                                           const float* __restrict__ Q,
                                           const float* __restrict__ w,
                                           const float* __restrict__ qmask,
                                           u16* __restrict__ S1g,
                                           _Float16* __restrict__ Tu_part,
                                           float* __restrict__ Z_part, int B) {
  __shared__ u16 ldsA[128 * PAD];  // phase1: C^T[i][d]; phase3: Cnat[d][i]
  __shared__ u16 ldsB[64 * PAD];   // phase1: Qw^T[j][d]; phase3: E^T[j][i]
                                   // row pad (16B): inv[i] stash
  __shared__ float scp4[4][128];
  __shared__ float sqp8[8][64];
  __shared__ float scL[128];
  __shared__ float sqs[64];
  __shared__ float mkS[64];
  int b = blockIdx.y, bx = blockIdx.x;
  int i0 = bx * 128, t = threadIdx.x;
  const float* Cb = C + (size_t)b * DD * LC;
  const float* Qb = Q + (size_t)b * DD * LQ;
  if (t < 64) mkS[t] = qmask[b * LQ + t];
  // --- phase 1 staging: C^T (bf16, transposed) + sc partials ---
  {
    int i_st = t & 127, dh = t >> 7;  // dh in [0,4): 32 d each
    const float* Cp = Cb + (size_t)dh * 32 * LC + i0 + i_st;
    float scp = 0.f;
#pragma unroll
    for (int dp = 0; dp < 16; ++dp) {
      int d = dh * 32 + 2 * dp;
      float c0 = Cp[(size_t)(2 * dp) * LC];
      float c1 = Cp[(size_t)(2 * dp + 1) * LC];
      scp = fmaf(c0, w[d], fmaf(c1, w[d + 1], scp));
      *(u32*)&ldsA[i_st * PAD + d] = pack2(c0, c1);
    }
    scp4[dh][i_st] = scp;
  }
  // Qw^T staging + sq partials
  {
    int j = t & 63, dg = t >> 6;  // dg in [0,8): 16 d each
    const float* Qp = Qb + j;
    float sqp = 0.f;
#pragma unroll
    for (int dp = 0; dp < 8; ++dp) {
      int d = dg * 16 + 2 * dp;
      float q0 = Qp[(size_t)d * LQ];
      float q1 = Qp[(size_t)(d + 1) * LQ];
      sqp = fmaf(q0, w[DD + d], fmaf(q1, w[DD + d + 1], sqp));
      *(u32*)&ldsB[j * PAD + d] = pack2(q0 * w[2 * DD + d], q1 * w[2 * DD + d + 1]);
    }
    sqp8[dg][j] = sqp;
  }
  __syncthreads();
  if (t < 128) {
    scL[t] = scp4[0][t] + scp4[1][t] + scp4[2][t] + scp4[3][t];
  } else if (t < 192) {
    int j = t - 128;
    float s = 0.f;
#pragma unroll
    for (int g = 0; g < 8; ++g) s += sqp8[g][j];
    sqs[j] = s;
  }
  // --- phase 2: S-GEMM; wave wv owns m-tile wv (16 i rows) ---
  int lane = t & 63, wv = t >> 6;
  int lr = lane & 15, kg = lane >> 4;
  f32x4 acc[4];
#pragma unroll
  for (int nt = 0; nt < 4; ++nt) acc[nt] = (f32x4){0.f, 0.f, 0.f, 0.f};
#pragma unroll
  for (int ks = 0; ks < 4; ++ks) {
    bf16x8 af = *(bf16x8*)&ldsA[(wv * 16 + lr) * PAD + ks * 32 + kg * 8];
    bf16x8 bf[4];
#pragma unroll
    for (int nt = 0; nt < 4; ++nt)
      bf[nt] = *(bf16x8*)&ldsB[(nt * 16 + lr) * PAD + ks * 32 + kg * 8];
#pragma unroll
    for (int nt = 0; nt < 4; ++nt)
      acc[nt] = __builtin_amdgcn_mfma_f32_16x16x32_bf16(af, bf[nt], acc[nt], 0, 0, 0);
  }
  __syncthreads();  // all MFMA reads done; scL/sqs final
  // --- epilogue: E=exp(S+sc+sq); rowsum(mask*E) -> inv; E^T -> ldsB ---
  {
    int ib = wv * 16 + kg * 4;
    float ev[4][4];
    float ps[4] = {0.f, 0.f, 0.f, 0.f};
#pragma unroll
    for (int nt = 0; nt < 4; ++nt) {
      int j = nt * 16 + lr;
      float sqv = sqs[j];
      float mkv = mkS[j];
#pragma unroll
      for (int r = 0; r < 4; ++r) {
        float e = __expf(acc[nt][r] + scL[ib + r] + sqv);
        ev[nt][r] = e;
        ps[r] = fmaf(mkv, e, ps[r]);
      }
    }
#pragma unroll
    for (int r = 0; r < 4; ++r) {
      ps[r] += __shfl_xor(ps[r], 1, 64);
      ps[r] += __shfl_xor(ps[r], 2, 64);
      ps[r] += __shfl_xor(ps[r], 4, 64);
      ps[r] += __shfl_xor(ps[r], 8, 64);
    }
#pragma unroll
    for (int nt = 0; nt < 4; ++nt) {
      int j = nt * 16 + lr;
      u32 pk[2] = {pack2(ev[nt][0], ev[nt][1]), pack2(ev[nt][2], ev[nt][3])};
      *(uint2*)&ldsB[j * PAD + ib] = *(uint2*)pk;
    }
    if (lr == 0) {
#pragma unroll
      for (int r = 0; r < 4; ++r) {
        int i = ib + r;
        ((float*)&ldsB[(i & 63) * PAD + 128])[i >> 6] = 1.f / fmaxf(ps[r], 1e-30f);
      }
    }
  }
  // --- Cnat staging: C[d][i] bf16 (overlays ldsA); 32 i per thread ---
  {
    int d = t >> 2, q = t & 3;
    const float* src = Cb + (size_t)d * LC + i0 + q * 32;
    u32 pk[16];
#pragma unroll
    for (int ip = 0; ip < 8; ++ip) {
      float4 v = *(const float4*)&src[ip * 4];
      pk[2 * ip] = pack2(v.x, v.y);
      pk[2 * ip + 1] = pack2(v.z, v.w);
    }
#pragma unroll
    for (int q4 = 0; q4 < 4; ++q4)
      *(uint4*)&ldsA[d * PAD + q * 32 + q4 * 8] = *(uint4*)&pk[q4 * 4];
  }
  __syncthreads();
  // --- phase 3 ---
  // Z[j] over this block's 128 i (b128 LDS reads; same fp32 sum order)
  if (t < 64) {
    const uint4* row = (const uint4*)&ldsB[t * PAD];
    float z = 0.f;
#pragma unroll
    for (int q = 0; q < 16; ++q) {
      uint4 v = row[q];
      z += b2f((u16)v.x) + b2f((u16)(v.x >> 16)) + b2f((u16)v.y) +
           b2f((u16)(v.y >> 16)) + b2f((u16)v.z) + b2f((u16)(v.z >> 16)) +
           b2f((u16)v.w) + b2f((u16)(v.w >> 16));
    }
    Z_part[((size_t)bx * B + b) * LQ + t] = z;
  }
  // S1 dump: S1[i][j] = mask[j]*inv[i]*E[i][j]; 16 j per thread
  {
    int i = t >> 2, q4 = t & 3;
    float inv = ((float*)&ldsB[(i & 63) * PAD + 128])[i >> 6];
    u32 opk[8];
#pragma unroll
    for (int q = 0; q < 8; ++q) {
      int j = q4 * 16 + 2 * q;
      float a0 = b2f(ldsB[j * PAD + i]) * mkS[j] * inv;
      float a1 = b2f(ldsB[(j + 1) * PAD + i]) * mkS[j + 1] * inv;
      opk[q] = pack2(a0, a1);
    }
    u16* dst = S1g + ((size_t)b * LC + i0 + i) * LQ + q4 * 16;
    *(uint4*)&dst[0] = *(uint4*)&opk[0];
    *(uint4*)&dst[8] = *(uint4*)&opk[4];
  }
  // T-GEMM: Tp[j][d] = sum_i E[i][j]*C[d][i]; wave wv owns d m-tile wv
  f32x4 tacc[4];
#pragma unroll
  for (int nt = 0; nt < 4; ++nt) tacc[nt] = (f32x4){0.f, 0.f, 0.f, 0.f};
#pragma unroll
  for (int ks = 0; ks < 4; ++ks) {
    bf16x8 af = *(bf16x8*)&ldsA[(wv * 16 + lr) * PAD + ks * 32 + kg * 8];
    bf16x8 bf[4];
#pragma unroll
    for (int nt = 0; nt < 4; ++nt)
      bf[nt] = *(bf16x8*)&ldsB[(nt * 16 + lr) * PAD + ks * 32 + kg * 8];
#pragma unroll
    for (int nt = 0; nt < 4; ++nt)
      tacc[nt] = __builtin_amdgcn_mfma_f32_16x16x32_bf16(af, bf[nt], tacc[nt], 0, 0, 0);
  }
  _Float16* Tp = Tu_part + ((size_t)bx * B + b) * LQ * DD;
#pragma unroll
  for (int nt = 0; nt < 4; ++nt) {
    int j = nt * 16 + lr;
    int db = wv * 16 + kg * 4;
    f16x4 h;
#pragma unroll
    for (int r = 0; r < 4; ++r) h[r] = (_Float16)tacc[nt][r];
    *(f16x4*)&Tp[(size_t)j * DD + db] = h;
  }
}

// K3b: Tz = (sum_p Tu_part)/Z -> TzT bf16; also Q -> Qbf16[d][j]
__global__ __launch_bounds__(256) void k3b(const _Float16* __restrict__ Tu_part,
                                           const float* __restrict__ Z_part,
                                           const float* __restrict__ Q,
                                           u16* __restrict__ TzT,
                                           u16* __restrict__ Qbf, int B) {
  __shared__ float Tsm[16][68];
  __shared__ float ziL[64];
  int b = blockIdx.y, d0 = blockIdx.x * 16;
  int t = threadIdx.x;
  // Q -> bf16 (independent)
  {
    int dq = d0 + (t >> 4), jq = (t & 15) * 4;
    const float* qp = Q + ((size_t)b * DD + dq) * LQ + jq;
    u32 pk[2] = {pack2(qp[0], qp[1]), pack2(qp[2], qp[3])};
    *(uint2*)&Qbf[((size_t)b * DD + dq) * LQ + jq] = *(uint2*)pk;
  }
  // vectorized partial reduction: thread -> (j, 4 consecutive d)
  {
    int j = t >> 2, dseg = t & 3;
    float acc[4] = {0.f, 0.f, 0.f, 0.f};
#pragma unroll
    for (int p = 0; p < NPART; ++p) {
      f16x4 v = *(const f16x4*)&Tu_part[((size_t)p * B + b) * LQ * DD +
                                        (size_t)j * DD + d0 + dseg * 4];
#pragma unroll
      for (int r = 0; r < 4; ++r) acc[r] += (float)v[r];
    }
#pragma unroll
    for (int r = 0; r < 4; ++r) Tsm[dseg * 4 + r][j] = acc[r];
  }
  if (t < 64) {
    float z = 0.f;
#pragma unroll
    for (int p = 0; p < NPART; ++p) z += Z_part[((size_t)p * B + b) * LQ + t];
    ziL[t] = 1.f / z;
  }
  __syncthreads();
  if (t < 128) {
    int d = t >> 3, seg = t & 7;
    u32 pk[4];
#pragma unroll
    for (int q = 0; q < 4; ++q) {
      int j = seg * 8 + q * 2;
      pk[q] = pack2(Tsm[d][j] * ziL[j], Tsm[d][j + 1] * ziL[j + 1]);
    }
    *(uint4*)&TzT[((size_t)b * DD + d0 + d) * LQ + seg * 8] = *(uint4*)pk;
  }
}

// K4: LDS-free. A-op = S1 rows i, B-op = Q/Tz rows d -> float4 loads/stores.
__global__ __launch_bounds__(256) void k4(const u16* __restrict__ S1g,
                                          const u16* __restrict__ Qbf,
                                          const u16* __restrict__ TzT,
                                          const float* __restrict__ C,
                                          float* __restrict__ out) {
  int b = blockIdx.y, i0 = blockIdx.x * 64, t = threadIdx.x;
  int lane = t & 63, wv = t >> 6;
  int lr = lane & 15, kg = lane >> 4;
  bf16x8 Af[2];
  {
    size_t ri = ((size_t)b * LC + i0 + wv * 16 + lr) * LQ;
    Af[0] = *(const bf16x8*)&S1g[ri + kg * 8];
    Af[1] = *(const bf16x8*)&S1g[ri + 32 + kg * 8];
  }
  const u16* Qb = Qbf + (size_t)b * DD * LQ;
  const u16* Tzb = TzT + (size_t)b * DD * LQ;
  const float* Cb = C + (size_t)b * DD * LC + i0;
  float* outb = out + (size_t)b * 4 * DD * LC + i0;
  int irow = wv * 16 + kg * 4;
#pragma unroll
  for (int nt = 0; nt < 8; ++nt) {
    int d = nt * 16 + lr;
    bf16x8 QB[2], TB[2];
#pragma unroll
    for (int ks = 0; ks < 2; ++ks) {
      QB[ks] = *(const bf16x8*)&Qb[(size_t)d * LQ + ks * 32 + kg * 8];
      TB[ks] = *(const bf16x8*)&Tzb[(size_t)d * LQ + ks * 32 + kg * 8];
    }
    f32x4 accA = {0.f, 0.f, 0.f, 0.f}, accB = {0.f, 0.f, 0.f, 0.f};
    accA = __builtin_amdgcn_mfma_f32_16x16x32_bf16(Af[0], QB[0], accA, 0, 0, 0);
    accA = __builtin_amdgcn_mfma_f32_16x16x32_bf16(Af[1], QB[1], accA, 0, 0, 0);
    accB = __builtin_amdgcn_mfma_f32_16x16x32_bf16(Af[0], TB[0], accB, 0, 0, 0);
    accB = __builtin_amdgcn_mfma_f32_16x16x32_bf16(Af[1], TB[1], accB, 0, 0, 0);
    float4 c4 = *(const float4*)&Cb[(size_t)d * LC + irow];
    float4 oA = make_float4(accA[0], accA[1], accA[2], accA[3]);
    float4 oCA = make_float4(c4.x * accA[0], c4.y * accA[1], c4.z * accA[2],
                             c4.w * accA[3]);
    float4 oCB = make_float4(c4.x * accB[0], c4.y * accB[1], c4.z * accB[2],
                             c4.w * accB[3]);
    *(float4*)&outb[(size_t)d * LC + irow] = c4;
    *(float4*)&outb[(size_t)(DD + d) * LC + irow] = oA;
    *(float4*)&outb[(size_t)(2 * DD + d) * LC + irow] = oCA;
    *(float4*)&outb[(size_t)(3 * DD + d) * LC + irow] = oCB;
  }
}

extern "C" void kernel_launch(void* const* d_in, const int* in_sizes, int n_in,
                              void* d_out, int out_size, void* d_ws, size_t ws_size,
                              hipStream_t stream) {
  const float* C = (const float*)d_in[0];
  const float* Q = (const float*)d_in[1];
  const float* qmask = (const float*)d_in[2];
  const float* w = (const float*)d_in[3];
  float* out = (float*)d_out;
  int B = in_sizes[2] / LQ;

  char* p = (char*)d_ws;
  u16* S1g = (u16*)p;              p += (size_t)B * LC * LQ * 2;
  u16* TzT = (u16*)p;              p += (size_t)B * DD * LQ * 2;
  u16* Qbf = (u16*)p;              p += (size_t)B * DD * LQ * 2;
  _Float16* Tu_part = (_Float16*)p; p += (size_t)NPART * B * LQ * DD * 2;
  float* Z_part = (float*)p;

  k13<<<dim3(LC / 128, B), 512, 0, stream>>>(C, Q, w, qmask, S1g, Tu_part, Z_part, B);
  k3b<<<dim3(DD / 16, B), 256, 0, stream>>>(Tu_part, Z_part, Q, TzT, Qbf, B);
  k4<<<dim3(LC / 64, B), 256, 0, stream>>>(S1g, Qbf, TzT, C, out);
}

// Round 20
// 62.721 us; speedup vs baseline: 1.0336x; 1.0092x over previous
//
#include <hip/hip_runtime.h>

#define LC 2048
#define DD 128
#define LQ 64
#define NPART 16
#define PAD 136

typedef unsigned short u16;
typedef unsigned int u32;
typedef __attribute__((ext_vector_type(8))) short bf16x8;
typedef __attribute__((ext_vector_type(4))) float f32x4;
typedef __attribute__((ext_vector_type(4))) _Float16 f16x4;

__device__ inline float b2f(u16 u) { return __uint_as_float(((u32)u) << 16); }
// pack2(a,b): a -> low 16, b -> high 16, RNE. Single HW instr on gfx950.
__device__ inline u32 pack2(float a, float b) {
  u32 r;
  asm("v_cvt_pk_bf16_f32 %0, %1, %2" : "=v"(r) : "v"(a), "v"(b));
  return r;
}

// K13: 128-i chunk, 8 waves: MFMA S-GEMM + exp + row-softmax -> S1g + Z + T partial
// Cnat loads issued in phase 1 (T14 async-stage), written to LDS after sync2.
__global__ __launch_bounds__(512) void k13(const float* __restrict__ C,
                                           const float* __restrict__ Q,
                                           const float* __restrict__ w,
                                           const float* __restrict__ qmask,
                                           u16* __restrict__ S1g,
                                           _Float16* __restrict__ Tu_part,
                                           float* __restrict__ Z_part, int B) {
  __shared__ u16 ldsA[128 * PAD];  // phase1: C^T[i][d]; phase3: Cnat[d][i]
  __shared__ u16 ldsB[64 * PAD];   // phase1: Qw^T[j][d]; phase3: E^T[j][i]
                                   // row pad (16B): inv[i] stash
  __shared__ float scp4[4][128];
  __shared__ float sqp8[8][64];
  __shared__ float scL[128];
  __shared__ float sqs[64];
  __shared__ float mkS[64];
  int b = blockIdx.y, bx = blockIdx.x;
  int i0 = bx * 128, t = threadIdx.x;
  const float* Cb = C + (size_t)b * DD * LC;
  const float* Qb = Q + (size_t)b * DD * LQ;
  if (t < 64) mkS[t] = qmask[b * LQ + t];
  // --- phase 1 staging: C^T (bf16, transposed) + sc partials ---
  {
    int i_st = t & 127, dh = t >> 7;  // dh in [0,4): 32 d each
    const float* Cp = Cb + (size_t)dh * 32 * LC + i0 + i_st;
    float scp = 0.f;
#pragma unroll
    for (int dp = 0; dp < 16; ++dp) {
      int d = dh * 32 + 2 * dp;
      float c0 = Cp[(size_t)(2 * dp) * LC];
      float c1 = Cp[(size_t)(2 * dp + 1) * LC];
      scp = fmaf(c0, w[d], fmaf(c1, w[d + 1], scp));
      *(u32*)&ldsA[i_st * PAD + d] = pack2(c0, c1);
    }
    scp4[dh][i_st] = scp;
  }
  // Qw^T staging + sq partials
  {
    int j = t & 63, dg = t >> 6;  // dg in [0,8): 16 d each
    const float* Qp = Qb + j;
    float sqp = 0.f;
#pragma unroll
    for (int dp = 0; dp < 8; ++dp) {
      int d = dg * 16 + 2 * dp;
      float q0 = Qp[(size_t)d * LQ];
      float q1 = Qp[(size_t)(d + 1) * LQ];
      sqp = fmaf(q0, w[DD + d], fmaf(q1, w[DD + d + 1], sqp));
      *(u32*)&ldsB[j * PAD + d] = pack2(q0 * w[2 * DD + d], q1 * w[2 * DD + d + 1]);
    }
    sqp8[dg][j] = sqp;
  }
  // --- issue Cnat loads NOW (consumed after sync2); latency hides under MFMA ---
  int cd = t >> 2, cq = t & 3;
  float4 cn[8];
  {
    const float* csrc = Cb + (size_t)cd * LC + i0 + cq * 32;
#pragma unroll
    for (int ip = 0; ip < 8; ++ip) cn[ip] = *(const float4*)&csrc[ip * 4];
  }
  __syncthreads();
  if (t < 128) {
    scL[t] = scp4[0][t] + scp4[1][t] + scp4[2][t] + scp4[3][t];
  } else if (t < 192) {
    int j = t - 128;
    float s = 0.f;
#pragma unroll
    for (int g = 0; g < 8; ++g) s += sqp8[g][j];
    sqs[j] = s;
  }
  // --- phase 2: S-GEMM; wave wv owns m-tile wv (16 i rows) ---
  int lane = t & 63, wv = t >> 6;
  int lr = lane & 15, kg = lane >> 4;
  f32x4 acc[4];
#pragma unroll
  for (int nt = 0; nt < 4; ++nt) acc[nt] = (f32x4){0.f, 0.f, 0.f, 0.f};
#pragma unroll
  for (int ks = 0; ks < 4; ++ks) {
    bf16x8 af = *(bf16x8*)&ldsA[(wv * 16 + lr) * PAD + ks * 32 + kg * 8];
    bf16x8 bf[4];
#pragma unroll
    for (int nt = 0; nt < 4; ++nt)
      bf[nt] = *(bf16x8*)&ldsB[(nt * 16 + lr) * PAD + ks * 32 + kg * 8];
#pragma unroll
    for (int nt = 0; nt < 4; ++nt)
      acc[nt] = __builtin_amdgcn_mfma_f32_16x16x32_bf16(af, bf[nt], acc[nt], 0, 0, 0);
  }
  __syncthreads();  // all MFMA reads done; scL/sqs final
  // --- epilogue: E=exp(S+sc+sq); rowsum(mask*E) -> inv; E^T -> ldsB ---
  {
    int ib = wv * 16 + kg * 4;
    float ev[4][4];
    float ps[4] = {0.f, 0.f, 0.f, 0.f};
#pragma unroll
    for (int nt = 0; nt < 4; ++nt) {
      int j = nt * 16 + lr;
      float sqv = sqs[j];
      float mkv = mkS[j];
#pragma unroll
      for (int r = 0; r < 4; ++r) {
        float e = __expf(acc[nt][r] + scL[ib + r] + sqv);
        ev[nt][r] = e;
        ps[r] = fmaf(mkv, e, ps[r]);
      }
    }
#pragma unroll
    for (int r = 0; r < 4; ++r) {
      ps[r] += __shfl_xor(ps[r], 1, 64);
      ps[r] += __shfl_xor(ps[r], 2, 64);
      ps[r] += __shfl_xor(ps[r], 4, 64);
      ps[r] += __shfl_xor(ps[r], 8, 64);
    }
#pragma unroll
    for (int nt = 0; nt < 4; ++nt) {
      int j = nt * 16 + lr;
      u32 pk[2] = {pack2(ev[nt][0], ev[nt][1]), pack2(ev[nt][2], ev[nt][3])};
      *(uint2*)&ldsB[j * PAD + ib] = *(uint2*)pk;
    }
    if (lr == 0) {
#pragma unroll
      for (int r = 0; r < 4; ++r) {
        int i = ib + r;
        ((float*)&ldsB[(i & 63) * PAD + 128])[i >> 6] = 1.f / fmaxf(ps[r], 1e-30f);
      }
    }
  }
  // --- Cnat write-late: pack pre-loaded regs -> ldsA (overlays C^T) ---
  {
    u32 pk[16];
#pragma unroll
    for (int ip = 0; ip < 8; ++ip) {
      pk[2 * ip] = pack2(cn[ip].x, cn[ip].y);
      pk[2 * ip + 1] = pack2(cn[ip].z, cn[ip].w);
    }
#pragma unroll
    for (int q4 = 0; q4 < 4; ++q4)
      *(uint4*)&ldsA[cd * PAD + cq * 32 + q4 * 8] = *(uint4*)&pk[q4 * 4];
  }
  __syncthreads();
  // --- phase 3 ---
  // Z[j] over this block's 128 i (b128 LDS reads; same fp32 sum order)
  if (t < 64) {
    const uint4* row = (const uint4*)&ldsB[t * PAD];
    float z = 0.f;
#pragma unroll
    for (int q = 0; q < 16; ++q) {
      uint4 v = row[q];
      z += b2f((u16)v.x) + b2f((u16)(v.x >> 16)) + b2f((u16)v.y) +
           b2f((u16)(v.y >> 16)) + b2f((u16)v.z) + b2f((u16)(v.z >> 16)) +
           b2f((u16)v.w) + b2f((u16)(v.w >> 16));
    }
    Z_part[((size_t)bx * B + b) * LQ + t] = z;
  }
  // S1 dump: S1[i][j] = mask[j]*inv[i]*E[i][j]; 16 j per thread
  {
    int i = t >> 2, q4 = t & 3;
    float inv = ((float*)&ldsB[(i & 63) * PAD + 128])[i >> 6];
    u32 opk[8];
#pragma unroll
    for (int q = 0; q < 8; ++q) {
      int j = q4 * 16 + 2 * q;
      float a0 = b2f(ldsB[j * PAD + i]) * mkS[j] * inv;
      float a1 = b2f(ldsB[(j + 1) * PAD + i]) * mkS[j + 1] * inv;
      opk[q] = pack2(a0, a1);
    }
    u16* dst = S1g + ((size_t)b * LC + i0 + i) * LQ + q4 * 16;
    *(uint4*)&dst[0] = *(uint4*)&opk[0];
    *(uint4*)&dst[8] = *(uint4*)&opk[4];
  }
  // T-GEMM: Tp[j][d] = sum_i E[i][j]*C[d][i]; wave wv owns d m-tile wv
  f32x4 tacc[4];
#pragma unroll
  for (int nt = 0; nt < 4; ++nt) tacc[nt] = (f32x4){0.f, 0.f, 0.f, 0.f};
#pragma unroll
  for (int ks = 0; ks < 4; ++ks) {
    bf16x8 af = *(bf16x8*)&ldsA[(wv * 16 + lr) * PAD + ks * 32 + kg * 8];
    bf16x8 bf[4];
#pragma unroll
    for (int nt = 0; nt < 4; ++nt)
      bf[nt] = *(bf16x8*)&ldsB[(nt * 16 + lr) * PAD + ks * 32 + kg * 8];
#pragma unroll
    for (int nt = 0; nt < 4; ++nt)
      tacc[nt] = __builtin_amdgcn_mfma_f32_16x16x32_bf16(af, bf[nt], tacc[nt], 0, 0, 0);
  }
  _Float16* Tp = Tu_part + ((size_t)bx * B + b) * LQ * DD;
#pragma unroll
  for (int nt = 0; nt < 4; ++nt) {
    int j = nt * 16 + lr;
    int db = wv * 16 + kg * 4;
    f16x4 h;
#pragma unroll
    for (int r = 0; r < 4; ++r) h[r] = (_Float16)tacc[nt][r];
    *(f16x4*)&Tp[(size_t)j * DD + db] = h;
  }
}

// K3b: Tz = (sum_p Tu_part)/Z -> TzT bf16; also Q -> Qbf16[d][j]
__global__ __launch_bounds__(256) void k3b(const _Float16* __restrict__ Tu_part,
                                           const float* __restrict__ Z_part,
                                           const float* __restrict__ Q,
                                           u16* __restrict__ TzT,
                                           u16* __restrict__ Qbf, int B) {
  __shared__ float Tsm[16][68];
  __shared__ float ziL[64];
  int b = blockIdx.y, d0 = blockIdx.x * 16;
  int t = threadIdx.x;
  // Q -> bf16 (independent)
  {
    int dq = d0 + (t >> 4), jq = (t & 15) * 4;
    const float* qp = Q + ((size_t)b * DD + dq) * LQ + jq;
    u32 pk[2] = {pack2(qp[0], qp[1]), pack2(qp[2], qp[3])};
    *(uint2*)&Qbf[((size_t)b * DD + dq) * LQ + jq] = *(uint2*)pk;
  }
  // vectorized partial reduction: thread -> (j, 4 consecutive d)
  {
    int j = t >> 2, dseg = t & 3;
    float acc[4] = {0.f, 0.f, 0.f, 0.f};
#pragma unroll
    for (int p = 0; p < NPART; ++p) {
      f16x4 v = *(const f16x4*)&Tu_part[((size_t)p * B + b) * LQ * DD +
                                        (size_t)j * DD + d0 + dseg * 4];
#pragma unroll
      for (int r = 0; r < 4; ++r) acc[r] += (float)v[r];
    }
#pragma unroll
    for (int r = 0; r < 4; ++r) Tsm[dseg * 4 + r][j] = acc[r];
  }
  if (t < 64) {
    float z = 0.f;
#pragma unroll
    for (int p = 0; p < NPART; ++p) z += Z_part[((size_t)p * B + b) * LQ + t];
    ziL[t] = 1.f / z;
  }
  __syncthreads();
  if (t < 128) {
    int d = t >> 3, seg = t & 7;
    u32 pk[4];
#pragma unroll
    for (int q = 0; q < 4; ++q) {
      int j = seg * 8 + q * 2;
      pk[q] = pack2(Tsm[d][j] * ziL[j], Tsm[d][j + 1] * ziL[j + 1]);
    }
    *(uint4*)&TzT[((size_t)b * DD + d0 + d) * LQ + seg * 8] = *(uint4*)pk;
  }
}

// K4: LDS-free. A-op = S1 rows i, B-op = Q/Tz rows d -> float4 loads/stores.
__global__ __launch_bounds__(256) void k4(const u16* __restrict__ S1g,
                                          const u16* __restrict__ Qbf,
                                          const u16* __restrict__ TzT,
                                          const float* __restrict__ C,
                                          float* __restrict__ out) {
  int b = blockIdx.y, i0 = blockIdx.x * 64, t = threadIdx.x;
  int lane = t & 63, wv = t >> 6;
  int lr = lane & 15, kg = lane >> 4;
  bf16x8 Af[2];
  {
    size_t ri = ((size_t)b * LC + i0 + wv * 16 + lr) * LQ;
    Af[0] = *(const bf16x8*)&S1g[ri + kg * 8];
    Af[1] = *(const bf16x8*)&S1g[ri + 32 + kg * 8];
  }
  const u16* Qb = Qbf + (size_t)b * DD * LQ;
  const u16* Tzb = TzT + (size_t)b * DD * LQ;
  const float* Cb = C + (size_t)b * DD * LC + i0;
  float* outb = out + (size_t)b * 4 * DD * LC + i0;
  int irow = wv * 16 + kg * 4;
#pragma unroll
  for (int nt = 0; nt < 8; ++nt) {
    int d = nt * 16 + lr;
    bf16x8 QB[2], TB[2];
#pragma unroll
    for (int ks = 0; ks < 2; ++ks) {
      QB[ks] = *(const bf16x8*)&Qb[(size_t)d * LQ + ks * 32 + kg * 8];
      TB[ks] = *(const bf16x8*)&Tzb[(size_t)d * LQ + ks * 32 + kg * 8];
    }
    f32x4 accA = {0.f, 0.f, 0.f, 0.f}, accB = {0.f, 0.f, 0.f, 0.f};
    accA = __builtin_amdgcn_mfma_f32_16x16x32_bf16(Af[0], QB[0], accA, 0, 0, 0);
    accA = __builtin_amdgcn_mfma_f32_16x16x32_bf16(Af[1], QB[1], accA, 0, 0, 0);
    accB = __builtin_amdgcn_mfma_f32_16x16x32_bf16(Af[0], TB[0], accB, 0, 0, 0);
    accB = __builtin_amdgcn_mfma_f32_16x16x32_bf16(Af[1], TB[1], accB, 0, 0, 0);
    float4 c4 = *(const float4*)&Cb[(size_t)d * LC + irow];
    float4 oA = make_float4(accA[0], accA[1], accA[2], accA[3]);
    float4 oCA = make_float4(c4.x * accA[0], c4.y * accA[1], c4.z * accA[2],
                             c4.w * accA[3]);
    float4 oCB = make_float4(c4.x * accB[0], c4.y * accB[1], c4.z * accB[2],
                             c4.w * accB[3]);
    *(float4*)&outb[(size_t)d * LC + irow] = c4;
    *(float4*)&outb[(size_t)(DD + d) * LC + irow] = oA;
    *(float4*)&outb[(size_t)(2 * DD + d) * LC + irow] = oCA;
    *(float4*)&outb[(size_t)(3 * DD + d) * LC + irow] = oCB;
  }
}

extern "C" void kernel_launch(void* const* d_in, const int* in_sizes, int n_in,
                              void* d_out, int out_size, void* d_ws, size_t ws_size,
                              hipStream_t stream) {
  const float* C = (const float*)d_in[0];
  const float* Q = (const float*)d_in[1];
  const float* qmask = (const float*)d_in[2];
  const float* w = (const float*)d_in[3];
  float* out = (float*)d_out;
  int B = in_sizes[2] / LQ;

  char* p = (char*)d_ws;
  u16* S1g = (u16*)p;              p += (size_t)B * LC * LQ * 2;
  u16* TzT = (u16*)p;              p += (size_t)B * DD * LQ * 2;
  u16* Qbf = (u16*)p;              p += (size_t)B * DD * LQ * 2;
  _Float16* Tu_part = (_Float16*)p; p += (size_t)NPART * B * LQ * DD * 2;
  float* Z_part = (float*)p;

  k13<<<dim3(LC / 128, B), 512, 0, stream>>>(C, Q, w, qmask, S1g, Tu_part, Z_part, B);
  k3b<<<dim3(DD / 16, B), 256, 0, stream>>>(Tu_part, Z_part, Q, TzT, Qbf, B);
  k4<<<dim3(LC / 64, B), 256, 0, stream>>>(S1g, Qbf, TzT, C, out);
}